// Round 1
// baseline (641.797 us; speedup 1.0000x reference)
//
#include <hip/hip_runtime.h>
#include <hip/hip_bf16.h>

// B=32, S=2048, H=1024, U=1024. M = B*S = 65536 rows.
// score[b,s] = sum_u tanh(enc[b,s,:]@W1[:,u] + W1b[u] + ph[b,u]) * Vw[u]  (+Vb, cancels in softmax)
// out = softmax_s(score)

typedef __bf16 bf16x8 __attribute__((ext_vector_type(8)));
typedef float  f32x4  __attribute__((ext_vector_type(4)));

#define HDIM 1024
#define UDIM 1024
#define SDIM 2048
#define MROWS 65536
#define BM 128
#define BN 128
#define BK 32
#define LDK 40   // padded LDS K-stride (bf16 elems): 80B rows, 16B-aligned, ~2-way banks (free)

__device__ inline unsigned short f2bf(float x) {
    return __builtin_bit_cast(unsigned short, (__bf16)x);
}

// ---------------- prep: W1 [H,U] fp32 -> W1T [U,H] bf16 ----------------
__global__ void w1t_kernel(const float* __restrict__ W1, unsigned short* __restrict__ W1T) {
    __shared__ float tile[32][33];
    int bx = blockIdx.x;   // u tile
    int by = blockIdx.y;   // h tile
    int tx = threadIdx.x, ty = threadIdx.y;   // (32,8)
#pragma unroll
    for (int r = 0; r < 4; ++r) {
        int h = by * 32 + ty + r * 8;
        int u = bx * 32 + tx;
        tile[ty + r * 8][tx] = W1[h * UDIM + u];
    }
    __syncthreads();
#pragma unroll
    for (int r = 0; r < 4; ++r) {
        int u = bx * 32 + ty + r * 8;
        int h = by * 32 + tx;
        W1T[u * HDIM + h] = f2bf(tile[tx][ty + r * 8]);
    }
}

// ---------------- prep: ph partials (split-K over h) ----------------
__global__ void php_kernel(const float* __restrict__ hn, const float* __restrict__ W2,
                           float* __restrict__ php) {
    int u = (blockIdx.x & 3) * 256 + threadIdx.x;
    int b = blockIdx.y;
    int hc = blockIdx.z;           // 8 chunks of 128
    int h0 = hc * 128;
    float acc = 0.f;
#pragma unroll 8
    for (int h = h0; h < h0 + 128; ++h)
        acc = fmaf(hn[b * HDIM + h], W2[h * UDIM + u], acc);
    php[(hc * 32 + b) * UDIM + u] = acc;
}

__global__ void ph_combine(const float* __restrict__ php, const float* __restrict__ W1b,
                           const float* __restrict__ W2b, float* __restrict__ ph) {
    int idx = blockIdx.x * 256 + threadIdx.x;   // 32768
    int u = idx & (UDIM - 1);
    int b = idx >> 10;
    float acc = W1b[u] + W2b[u];
#pragma unroll
    for (int p = 0; p < 8; ++p) acc += php[(p * 32 + b) * UDIM + u];
    ph[idx] = acc;
}

// ---------------- main fused GEMM + tanh + V-dot ----------------
__global__ __launch_bounds__(256) void score_kernel(
    const float* __restrict__ enc, const unsigned short* __restrict__ W1T,
    const float* __restrict__ ph, const float* __restrict__ Vw,
    float* __restrict__ part) {
    __shared__ unsigned short As[BM * LDK];   // 10240 B
    __shared__ unsigned short Bs[BN * LDK];   // 10240 B

    const int bx = blockIdx.x;
    const int tile_n = bx & 7;       // n-fastest: 8 consecutive blocks share one A-tile
    const int tile_m = bx >> 3;
    const int t = threadIdx.x;
    const int lane = t & 63;
    const int wid = t >> 6;
    const int wm = wid >> 1, wn = wid & 1;

    const int row0 = tile_m * BM;
    const int col0 = tile_n * BN;

    f32x4 acc[4][4];
#pragma unroll
    for (int i = 0; i < 4; ++i)
#pragma unroll
        for (int j = 0; j < 4; ++j)
            acc[i][j] = (f32x4){0.f, 0.f, 0.f, 0.f};

    const int mrow = lane & 15;
    const int kq = (lane >> 4) * 8;

    for (int kt = 0; kt < HDIM; kt += BK) {
        __syncthreads();   // previous iteration's frag reads complete
        // stage A: 128x32 fp32 -> bf16 ; 4 float4 chunks per thread
#pragma unroll
        for (int i = 0; i < 4; ++i) {
            int c = t + 256 * i;
            int r = c >> 3;
            int kc = (c & 7) * 4;
            const float4 f = *(const float4*)(enc + (size_t)(row0 + r) * HDIM + kt + kc);
            ushort4 h;
            h.x = f2bf(f.x); h.y = f2bf(f.y); h.z = f2bf(f.z); h.w = f2bf(f.w);
            *(ushort4*)(As + r * LDK + kc) = h;
        }
        // stage B: 128x32 bf16 ; 2 16B chunks per thread
#pragma unroll
        for (int i = 0; i < 2; ++i) {
            int c = t + 256 * i;
            int r = c >> 2;
            int kc = (c & 3) * 8;
            const uint4 v = *(const uint4*)(W1T + (size_t)(col0 + r) * HDIM + kt + kc);
            *(uint4*)(Bs + r * LDK + kc) = v;
        }
        __syncthreads();

        bf16x8 a[4], bb[4];
#pragma unroll
        for (int i = 0; i < 4; ++i)
            a[i] = *reinterpret_cast<const bf16x8*>(As + (wm * 64 + i * 16 + mrow) * LDK + kq);
#pragma unroll
        for (int j = 0; j < 4; ++j)
            bb[j] = *reinterpret_cast<const bf16x8*>(Bs + (wn * 64 + j * 16 + mrow) * LDK + kq);
#pragma unroll
        for (int i = 0; i < 4; ++i)
#pragma unroll
            for (int j = 0; j < 4; ++j)
                acc[i][j] = __builtin_amdgcn_mfma_f32_16x16x32_bf16(a[i], bb[j], acc[i][j], 0, 0, 0);
    }

    // epilogue: pe -> tanh -> *Vw -> reduce over u within tile -> partial slice
    const int b = row0 >> 11;          // S=2048 rows per batch; BM divides S
    const int colg = lane & 15;        // C/D: col = lane&15
    const int rowq = (lane >> 4) * 4;  // C/D: row = quad*4 + reg
    float vw[4], phv[4];
#pragma unroll
    for (int j = 0; j < 4; ++j) {
        int u = col0 + wn * 64 + j * 16 + colg;
        vw[j] = Vw[u];
        phv[j] = ph[b * UDIM + u];
    }
#pragma unroll
    for (int i = 0; i < 4; ++i) {
#pragma unroll
        for (int r = 0; r < 4; ++r) {
            float s = 0.f;
#pragma unroll
            for (int j = 0; j < 4; ++j) {
                float pe = acc[i][j][r] + phv[j];
                s += tanhf(pe) * vw[j];
            }
            // reduce across the 16 cols (lanes within each 16-lane group)
            s += __shfl_xor(s, 1);
            s += __shfl_xor(s, 2);
            s += __shfl_xor(s, 4);
            s += __shfl_xor(s, 8);
            if (colg == 0) {
                int row = row0 + wm * 64 + i * 16 + rowq + r;
                part[(size_t)(tile_n * 2 + wn) * MROWS + row] = s;
            }
        }
    }
}

// ---------------- final: sum 16 partial slices + softmax over s ----------------
__global__ void softmax_kernel(const float* __restrict__ part, float* __restrict__ out) {
    int b = blockIdx.x;
    int t = threadIdx.x;   // 256
    __shared__ float sred[4];
    float v[8];
    float lmax = -3.4e38f;
#pragma unroll
    for (int i = 0; i < 8; ++i) {
        int s = t + i * 256;
        float sum = 0.f;
#pragma unroll
        for (int p = 0; p < 16; ++p) sum += part[(size_t)p * MROWS + b * SDIM + s];
        v[i] = sum;
        lmax = fmaxf(lmax, sum);
    }
#pragma unroll
    for (int off = 1; off < 64; off <<= 1) lmax = fmaxf(lmax, __shfl_xor(lmax, off));
    if ((t & 63) == 0) sred[t >> 6] = lmax;
    __syncthreads();
    float bmax = fmaxf(fmaxf(sred[0], sred[1]), fmaxf(sred[2], sred[3]));
    __syncthreads();
    float lsum = 0.f;
#pragma unroll
    for (int i = 0; i < 8; ++i) {
        v[i] = expf(v[i] - bmax);
        lsum += v[i];
    }
#pragma unroll
    for (int off = 1; off < 64; off <<= 1) lsum += __shfl_xor(lsum, off);
    if ((t & 63) == 0) sred[t >> 6] = lsum;
    __syncthreads();
    float inv = 1.0f / (sred[0] + sred[1] + sred[2] + sred[3]);
#pragma unroll
    for (int i = 0; i < 8; ++i) out[b * SDIM + t + i * 256] = v[i] * inv;
}

extern "C" void kernel_launch(void* const* d_in, const int* in_sizes, int n_in,
                              void* d_out, int out_size, void* d_ws, size_t ws_size,
                              hipStream_t stream) {
    const float* enc = (const float*)d_in[0];
    const float* hn  = (const float*)d_in[1];
    const float* W1  = (const float*)d_in[2];
    const float* W1b = (const float*)d_in[3];
    const float* W2  = (const float*)d_in[4];
    const float* W2b = (const float*)d_in[5];
    const float* Vw  = (const float*)d_in[6];
    // d_in[7] = V_b: softmax is shift-invariant per batch -> exactly cancels.
    float* out = (float*)d_out;

    char* ws = (char*)d_ws;
    unsigned short* W1T = (unsigned short*)ws;                          // 2 MB
    float* ph   = (float*)(ws + (2u << 20));                            // 128 KB
    float* php  = (float*)(ws + (2u << 20) + (128u << 10));             // 1 MB
    float* part = (float*)(ws + (2u << 20) + (128u << 10) + (1u << 20)); // 4 MB
    // total ws use: ~7.2 MB

    w1t_kernel<<<dim3(32, 32), dim3(32, 8), 0, stream>>>(W1, W1T);
    php_kernel<<<dim3(4, 32, 8), 256, 0, stream>>>(hn, W2, php);
    ph_combine<<<128, 256, 0, stream>>>(php, W1b, W2b, ph);
    score_kernel<<<dim3(4096), 256, 0, stream>>>(enc, W1T, ph, Vw, part);
    softmax_kernel<<<32, 256, 0, stream>>>(part, out);
}

// Round 2
// 614.993 us; speedup vs baseline: 1.0436x; 1.0436x over previous
//
#include <hip/hip_runtime.h>
#include <hip/hip_bf16.h>

// B=32, S=2048, H=1024, U=1024. M = B*S = 65536 rows.
// score[b,s] = sum_u tanh(enc[b,s,:]@W1[:,u] + W1b[u] + ph[b,u]) * Vw[u]  (+Vb cancels in softmax)
// out = softmax_s(score)

typedef __bf16 bf16x8 __attribute__((ext_vector_type(8)));
typedef float  f32x4  __attribute__((ext_vector_type(4)));

#define HDIM 1024
#define UDIM 1024
#define SDIM 2048
#define MROWS 65536
#define BM 128
#define BN 128
#define BK 32

__device__ inline unsigned short f2bf(float x) {
    return __builtin_bit_cast(unsigned short, (__bf16)x);
}

// async 16B global->LDS (m97: width=16 emits global_load_lds_dwordx4)
#define GLDS16(gp, lp)                                                              \
    __builtin_amdgcn_global_load_lds(                                               \
        (const __attribute__((address_space(1))) unsigned int*)(gp),                \
        (__attribute__((address_space(3))) unsigned int*)(lp), 16, 0, 0)

// ---------------- prep: enc fp32 -> bf16 (pure BW pass) ----------------
__global__ __launch_bounds__(256) void cvt_kernel(const float* __restrict__ in,
                                                  unsigned short* __restrict__ out) {
    size_t i = ((size_t)blockIdx.x * 256 + threadIdx.x) * 8;
    const float4 f0 = *(const float4*)(in + i);
    const float4 f1 = *(const float4*)(in + i + 4);
    ushort4 h0, h1;
    h0.x = f2bf(f0.x); h0.y = f2bf(f0.y); h0.z = f2bf(f0.z); h0.w = f2bf(f0.w);
    h1.x = f2bf(f1.x); h1.y = f2bf(f1.y); h1.z = f2bf(f1.z); h1.w = f2bf(f1.w);
    *(ushort4*)(out + i) = h0;
    *(ushort4*)(out + i + 4) = h1;
}

// ---------------- prep: W1 [H,U] fp32 -> W1T [U,H] bf16 ----------------
__global__ void w1t_kernel(const float* __restrict__ W1, unsigned short* __restrict__ W1T) {
    __shared__ float tile[32][33];
    int bx = blockIdx.x;   // u tile
    int by = blockIdx.y;   // h tile
    int tx = threadIdx.x, ty = threadIdx.y;   // (32,8)
#pragma unroll
    for (int r = 0; r < 4; ++r) {
        int h = by * 32 + ty + r * 8;
        int u = bx * 32 + tx;
        tile[ty + r * 8][tx] = W1[h * UDIM + u];
    }
    __syncthreads();
#pragma unroll
    for (int r = 0; r < 4; ++r) {
        int u = bx * 32 + ty + r * 8;
        int h = by * 32 + tx;
        W1T[u * HDIM + h] = f2bf(tile[tx][ty + r * 8]);
    }
}

// ---------------- prep: ph partials (split-K over h) ----------------
__global__ void php_kernel(const float* __restrict__ hn, const float* __restrict__ W2,
                           float* __restrict__ php) {
    int u = (blockIdx.x & 3) * 256 + threadIdx.x;
    int b = blockIdx.y;
    int hc = blockIdx.z;           // 8 chunks of 128
    int h0 = hc * 128;
    float acc = 0.f;
#pragma unroll 8
    for (int h = h0; h < h0 + 128; ++h)
        acc = fmaf(hn[b * HDIM + h], W2[h * UDIM + u], acc);
    php[(hc * 32 + b) * UDIM + u] = acc;
}

__global__ void ph_combine(const float* __restrict__ php, const float* __restrict__ W1b,
                           const float* __restrict__ W2b, float* __restrict__ ph) {
    int idx = blockIdx.x * 256 + threadIdx.x;   // 32768
    int u = idx & (UDIM - 1);
    int b = idx >> 10;
    float acc = W1b[u] + W2b[u];
#pragma unroll
    for (int p = 0; p < 8; ++p) acc += php[(p * 32 + b) * UDIM + u];
    ph[idx] = acc;
}

// ---------------- main fused GEMM (m97-style async staging) ----------------
__global__ __launch_bounds__(256) void score_kernel(
    const unsigned short* __restrict__ encb, const unsigned short* __restrict__ W1T,
    const float* __restrict__ ph, const float* __restrict__ Vw,
    float* __restrict__ part) {
    // unpadded, lane-ordered for global_load_lds (wave-uniform base + lane*16)
    __shared__ unsigned short As[BM * BK];   // 8192 B
    __shared__ unsigned short Bs[BN * BK];   // 8192 B

    const int bx = blockIdx.x;
    // XCD swizzle: bx&7 -> XCD (heuristic); each XCD owns a 64-tile m-slab,
    // n-fastest inside so the 8 sharers of an A-tile hit the same XCD L2.
    const int x = bx & 7;
    const int k = bx >> 3;
    const int tile_n = k & 7;
    const int tile_m = (x << 6) | (k >> 3);

    const int t = threadIdx.x;
    const int lane = t & 63;
    const int wid = t >> 6;
    const int wm = wid >> 1, wn = wid & 1;

    const int row0 = tile_m * BM;
    const int col0 = tile_n * BN;

    f32x4 acc[4][4];
#pragma unroll
    for (int i = 0; i < 4; ++i)
#pragma unroll
        for (int j = 0; j < 4; ++j)
            acc[i][j] = (f32x4){0.f, 0.f, 0.f, 0.f};

    const int mrow = lane & 15;
    const int kq = (lane >> 4) * 8;

    // per-issue chunk indices: c = issue*256 + wid*64 + lane; 16B per chunk
    // global: row = c>>2, koff = (c&3)*8 ; lds byte offset = c*16 (row-major [row][BK])
    const int c0 = wid * 64 + lane;
    const int c1 = c0 + 256;
    const unsigned ldsA0 = (unsigned)(wid * 64) * 16;          // wave-uniform base, issue 0
    const unsigned ldsA1 = ldsA0 + 256 * 16;                   // issue 1

    for (int kt = 0; kt < HDIM; kt += BK) {
        {
            const unsigned short* ga0 = encb + (size_t)(row0 + (c0 >> 2)) * HDIM + kt + (c0 & 3) * 8;
            const unsigned short* ga1 = encb + (size_t)(row0 + (c1 >> 2)) * HDIM + kt + (c1 & 3) * 8;
            const unsigned short* gb0 = W1T + (size_t)(col0 + (c0 >> 2)) * HDIM + kt + (c0 & 3) * 8;
            const unsigned short* gb1 = W1T + (size_t)(col0 + (c1 >> 2)) * HDIM + kt + (c1 & 3) * 8;
            GLDS16(ga0, (char*)As + ldsA0);
            GLDS16(ga1, (char*)As + ldsA1);
            GLDS16(gb0, (char*)Bs + ldsA0);
            GLDS16(gb1, (char*)Bs + ldsA1);
        }
        __syncthreads();   // drains vmcnt; LDS tile visible

        bf16x8 a[4], bb[4];
#pragma unroll
        for (int i = 0; i < 4; ++i)
            a[i] = *reinterpret_cast<const bf16x8*>(As + (wm * 64 + i * 16 + mrow) * BK + kq);
#pragma unroll
        for (int j = 0; j < 4; ++j)
            bb[j] = *reinterpret_cast<const bf16x8*>(Bs + (wn * 64 + j * 16 + mrow) * BK + kq);
#pragma unroll
        for (int i = 0; i < 4; ++i)
#pragma unroll
            for (int j = 0; j < 4; ++j)
                acc[i][j] = __builtin_amdgcn_mfma_f32_16x16x32_bf16(a[i], bb[j], acc[i][j], 0, 0, 0);
        __syncthreads();   // all waves done reading before next stage overwrites
    }

    // epilogue: +ph -> tanh -> *Vw -> reduce over u cols -> partial slice
    const int b = row0 >> 11;          // S=2048 rows per batch; BM divides S
    const int colg = lane & 15;        // C/D: col = lane&15
    const int rowq = (lane >> 4) * 4;  // C/D: row = quad*4 + reg
    float vw[4], phv[4];
#pragma unroll
    for (int j = 0; j < 4; ++j) {
        int u = col0 + wn * 64 + j * 16 + colg;
        vw[j] = Vw[u];
        phv[j] = ph[b * UDIM + u];
    }
#pragma unroll
    for (int i = 0; i < 4; ++i) {
#pragma unroll
        for (int r = 0; r < 4; ++r) {
            float s = 0.f;
#pragma unroll
            for (int j = 0; j < 4; ++j) {
                float pe = acc[i][j][r] + phv[j];
                s += tanhf(pe) * vw[j];
            }
            s += __shfl_xor(s, 1);
            s += __shfl_xor(s, 2);
            s += __shfl_xor(s, 4);
            s += __shfl_xor(s, 8);
            if (colg == 0) {
                int row = row0 + wm * 64 + i * 16 + rowq + r;
                part[(size_t)(tile_n * 2 + wn) * MROWS + row] = s;
            }
        }
    }
}

// ---------------- fallback GEMM (round-1, fp32 in-register convert) ----------------
#define LDK 40
__global__ __launch_bounds__(256) void score_kernel_f32(
    const float* __restrict__ enc, const unsigned short* __restrict__ W1T,
    const float* __restrict__ ph, const float* __restrict__ Vw,
    float* __restrict__ part) {
    __shared__ unsigned short As[BM * LDK];
    __shared__ unsigned short Bs[BN * LDK];

    const int bx = blockIdx.x;
    const int tile_n = bx & 7;
    const int tile_m = bx >> 3;
    const int t = threadIdx.x;
    const int lane = t & 63;
    const int wid = t >> 6;
    const int wm = wid >> 1, wn = wid & 1;

    const int row0 = tile_m * BM;
    const int col0 = tile_n * BN;

    f32x4 acc[4][4];
#pragma unroll
    for (int i = 0; i < 4; ++i)
#pragma unroll
        for (int j = 0; j < 4; ++j)
            acc[i][j] = (f32x4){0.f, 0.f, 0.f, 0.f};

    const int mrow = lane & 15;
    const int kq = (lane >> 4) * 8;

    for (int kt = 0; kt < HDIM; kt += BK) {
        __syncthreads();
#pragma unroll
        for (int i = 0; i < 4; ++i) {
            int c = t + 256 * i;
            int r = c >> 3;
            int kc = (c & 7) * 4;
            const float4 f = *(const float4*)(enc + (size_t)(row0 + r) * HDIM + kt + kc);
            ushort4 h;
            h.x = f2bf(f.x); h.y = f2bf(f.y); h.z = f2bf(f.z); h.w = f2bf(f.w);
            *(ushort4*)(As + r * LDK + kc) = h;
        }
#pragma unroll
        for (int i = 0; i < 2; ++i) {
            int c = t + 256 * i;
            int r = c >> 2;
            int kc = (c & 3) * 8;
            const uint4 v = *(const uint4*)(W1T + (size_t)(col0 + r) * HDIM + kt + kc);
            *(uint4*)(Bs + r * LDK + kc) = v;
        }
        __syncthreads();

        bf16x8 a[4], bb[4];
#pragma unroll
        for (int i = 0; i < 4; ++i)
            a[i] = *reinterpret_cast<const bf16x8*>(As + (wm * 64 + i * 16 + mrow) * LDK + kq);
#pragma unroll
        for (int j = 0; j < 4; ++j)
            bb[j] = *reinterpret_cast<const bf16x8*>(Bs + (wn * 64 + j * 16 + mrow) * LDK + kq);
#pragma unroll
        for (int i = 0; i < 4; ++i)
#pragma unroll
            for (int j = 0; j < 4; ++j)
                acc[i][j] = __builtin_amdgcn_mfma_f32_16x16x32_bf16(a[i], bb[j], acc[i][j], 0, 0, 0);
    }

    const int b = row0 >> 11;
    const int colg = lane & 15;
    const int rowq = (lane >> 4) * 4;
    float vw[4], phv[4];
#pragma unroll
    for (int j = 0; j < 4; ++j) {
        int u = col0 + wn * 64 + j * 16 + colg;
        vw[j] = Vw[u];
        phv[j] = ph[b * UDIM + u];
    }
#pragma unroll
    for (int i = 0; i < 4; ++i) {
#pragma unroll
        for (int r = 0; r < 4; ++r) {
            float s = 0.f;
#pragma unroll
            for (int j = 0; j < 4; ++j) {
                float pe = acc[i][j][r] + phv[j];
                s += tanhf(pe) * vw[j];
            }
            s += __shfl_xor(s, 1);
            s += __shfl_xor(s, 2);
            s += __shfl_xor(s, 4);
            s += __shfl_xor(s, 8);
            if (colg == 0) {
                int row = row0 + wm * 64 + i * 16 + rowq + r;
                part[(size_t)(tile_n * 2 + wn) * MROWS + row] = s;
            }
        }
    }
}

// ---------------- final: sum 16 partial slices + softmax over s ----------------
__global__ void softmax_kernel(const float* __restrict__ part, float* __restrict__ out) {
    int b = blockIdx.x;
    int t = threadIdx.x;   // 256
    __shared__ float sred[4];
    float v[8];
    float lmax = -3.4e38f;
#pragma unroll
    for (int i = 0; i < 8; ++i) {
        int s = t + i * 256;
        float sum = 0.f;
#pragma unroll
        for (int p = 0; p < 16; ++p) sum += part[(size_t)p * MROWS + b * SDIM + s];
        v[i] = sum;
        lmax = fmaxf(lmax, sum);
    }
#pragma unroll
    for (int off = 1; off < 64; off <<= 1) lmax = fmaxf(lmax, __shfl_xor(lmax, off));
    if ((t & 63) == 0) sred[t >> 6] = lmax;
    __syncthreads();
    float bmax = fmaxf(fmaxf(sred[0], sred[1]), fmaxf(sred[2], sred[3]));
    __syncthreads();
    float lsum = 0.f;
#pragma unroll
    for (int i = 0; i < 8; ++i) {
        v[i] = expf(v[i] - bmax);
        lsum += v[i];
    }
#pragma unroll
    for (int off = 1; off < 64; off <<= 1) lsum += __shfl_xor(lsum, off);
    if ((t & 63) == 0) sred[t >> 6] = lsum;
    __syncthreads();
    float inv = 1.0f / (sred[0] + sred[1] + sred[2] + sred[3]);
#pragma unroll
    for (int i = 0; i < 8; ++i) out[b * SDIM + t + i * 256] = v[i] * inv;
}

extern "C" void kernel_launch(void* const* d_in, const int* in_sizes, int n_in,
                              void* d_out, int out_size, void* d_ws, size_t ws_size,
                              hipStream_t stream) {
    const float* enc = (const float*)d_in[0];
    const float* hn  = (const float*)d_in[1];
    const float* W1  = (const float*)d_in[2];
    const float* W1b = (const float*)d_in[3];
    const float* W2  = (const float*)d_in[4];
    const float* W2b = (const float*)d_in[5];
    const float* Vw  = (const float*)d_in[6];
    // d_in[7] = V_b: softmax is shift-invariant per batch -> exactly cancels.
    float* out = (float*)d_out;

    char* ws = (char*)d_ws;
    const size_t ENCB_BYTES = (size_t)MROWS * HDIM * 2;        // 128 MB
    const size_t NEED = ENCB_BYTES + (2u << 20) + (128u << 10) + (1u << 20) + (4u << 20);

    if (ws_size >= NEED) {
        unsigned short* encb = (unsigned short*)ws;                                  // 128 MB
        unsigned short* W1T  = (unsigned short*)(ws + ENCB_BYTES);                   // 2 MB
        float* ph   = (float*)(ws + ENCB_BYTES + (2u << 20));                        // 128 KB
        float* php  = (float*)(ws + ENCB_BYTES + (2u << 20) + (128u << 10));         // 1 MB
        float* part = (float*)(ws + ENCB_BYTES + (2u << 20) + (128u << 10) + (1u << 20)); // 4 MB

        cvt_kernel<<<32768, 256, 0, stream>>>(enc, encb);
        w1t_kernel<<<dim3(32, 32), dim3(32, 8), 0, stream>>>(W1, W1T);
        php_kernel<<<dim3(4, 32, 8), 256, 0, stream>>>(hn, W2, php);
        ph_combine<<<128, 256, 0, stream>>>(php, W1b, W2b, ph);
        score_kernel<<<dim3(4096), 256, 0, stream>>>(encb, W1T, ph, Vw, part);
        softmax_kernel<<<32, 256, 0, stream>>>(part, out);
    } else {
        unsigned short* W1T = (unsigned short*)ws;                                   // 2 MB
        float* ph   = (float*)(ws + (2u << 20));
        float* php  = (float*)(ws + (2u << 20) + (128u << 10));
        float* part = (float*)(ws + (2u << 20) + (128u << 10) + (1u << 20));

        w1t_kernel<<<dim3(32, 32), dim3(32, 8), 0, stream>>>(W1, W1T);
        php_kernel<<<dim3(4, 32, 8), 256, 0, stream>>>(hn, W2, php);
        ph_combine<<<128, 256, 0, stream>>>(php, W1b, W2b, ph);
        score_kernel_f32<<<dim3(4096), 256, 0, stream>>>(enc, W1T, ph, Vw, part);
        softmax_kernel<<<32, 256, 0, stream>>>(part, out);
    }
}

// Round 3
// 596.450 us; speedup vs baseline: 1.0760x; 1.0311x over previous
//
#include <hip/hip_runtime.h>
#include <hip/hip_bf16.h>

// B=32, S=2048, H=1024, U=1024. M = B*S = 65536 rows.
// score[b,s] = sum_u tanh(enc[b,s,:]@W1[:,u] + W1b[u] + ph[b,u]) * Vw[u]  (+Vb cancels in softmax)
// out = softmax_s(score)

typedef __bf16 bf16x8 __attribute__((ext_vector_type(8)));
typedef float  f32x4  __attribute__((ext_vector_type(4)));

#define HDIM 1024
#define UDIM 1024
#define SDIM 2048
#define MROWS 65536
#define BM 128
#define BN 128
#define BK 32

__device__ inline unsigned short f2bf(float x) {
    return __builtin_bit_cast(unsigned short, (__bf16)x);
}

// fast tanh: tanh(x) = sign(x) * (1-e^{-2|x|})/(1+e^{-2|x|}).
// z in (0,1] -> no overflow path, no clamp. ~8 VALU ops vs ~40 for ocml tanhf.
// error ~1e-6 abs; propagated score error ~6e-7 << 1.9e-5 headroom.
__device__ inline float fast_tanh(float x) {
    float z = __expf(-2.0f * __builtin_fabsf(x));
    float t = __fdividef(1.0f - z, 1.0f + z);
    return __builtin_copysignf(t, x);
}

// async 16B global->LDS (m97: width=16 emits global_load_lds_dwordx4)
#define GLDS16(gp, lp)                                                              \
    __builtin_amdgcn_global_load_lds(                                               \
        (const __attribute__((address_space(1))) unsigned int*)(gp),                \
        (__attribute__((address_space(3))) unsigned int*)(lp), 16, 0, 0)

// ---------------- prep: enc fp32 -> bf16 (pure BW pass) ----------------
__global__ __launch_bounds__(256) void cvt_kernel(const float* __restrict__ in,
                                                  unsigned short* __restrict__ out) {
    size_t i = ((size_t)blockIdx.x * 256 + threadIdx.x) * 8;
    const float4 f0 = *(const float4*)(in + i);
    const float4 f1 = *(const float4*)(in + i + 4);
    ushort4 h0, h1;
    h0.x = f2bf(f0.x); h0.y = f2bf(f0.y); h0.z = f2bf(f0.z); h0.w = f2bf(f0.w);
    h1.x = f2bf(f1.x); h1.y = f2bf(f1.y); h1.z = f2bf(f1.z); h1.w = f2bf(f1.w);
    *(ushort4*)(out + i) = h0;
    *(ushort4*)(out + i + 4) = h1;
}

// ---------------- prep: W1 [H,U] fp32 -> W1T [U,H] bf16 ----------------
__global__ void w1t_kernel(const float* __restrict__ W1, unsigned short* __restrict__ W1T) {
    __shared__ float tile[32][33];
    int bx = blockIdx.x;   // u tile
    int by = blockIdx.y;   // h tile
    int tx = threadIdx.x, ty = threadIdx.y;   // (32,8)
#pragma unroll
    for (int r = 0; r < 4; ++r) {
        int h = by * 32 + ty + r * 8;
        int u = bx * 32 + tx;
        tile[ty + r * 8][tx] = W1[h * UDIM + u];
    }
    __syncthreads();
#pragma unroll
    for (int r = 0; r < 4; ++r) {
        int u = bx * 32 + ty + r * 8;
        int h = by * 32 + tx;
        W1T[u * HDIM + h] = f2bf(tile[tx][ty + r * 8]);
    }
}

// ---------------- prep: ph partials (split-K over h) ----------------
__global__ void php_kernel(const float* __restrict__ hn, const float* __restrict__ W2,
                           float* __restrict__ php) {
    int u = (blockIdx.x & 3) * 256 + threadIdx.x;
    int b = blockIdx.y;
    int hc = blockIdx.z;           // 8 chunks of 128
    int h0 = hc * 128;
    float acc = 0.f;
#pragma unroll 8
    for (int h = h0; h < h0 + 128; ++h)
        acc = fmaf(hn[b * HDIM + h], W2[h * UDIM + u], acc);
    php[(hc * 32 + b) * UDIM + u] = acc;
}

__global__ void ph_combine(const float* __restrict__ php, const float* __restrict__ W1b,
                           const float* __restrict__ W2b, float* __restrict__ ph) {
    int idx = blockIdx.x * 256 + threadIdx.x;   // 32768
    int u = idx & (UDIM - 1);
    int b = idx >> 10;
    float acc = W1b[u] + W2b[u];
#pragma unroll
    for (int p = 0; p < 8; ++p) acc += php[(p * 32 + b) * UDIM + u];
    ph[idx] = acc;
}

// ---------------- main fused GEMM (m97-style async staging) ----------------
__global__ __launch_bounds__(256) void score_kernel(
    const unsigned short* __restrict__ encb, const unsigned short* __restrict__ W1T,
    const float* __restrict__ ph, const float* __restrict__ Vw,
    float* __restrict__ part) {
    // unpadded, lane-ordered for global_load_lds (wave-uniform base + lane*16)
    __shared__ unsigned short As[BM * BK];   // 8192 B
    __shared__ unsigned short Bs[BN * BK];   // 8192 B

    const int bx = blockIdx.x;
    // XCD swizzle: bx&7 -> XCD; each XCD owns a 64-tile m-slab,
    // n-fastest inside so the 8 sharers of an A-tile hit the same XCD L2.
    const int x = bx & 7;
    const int k = bx >> 3;
    const int tile_n = k & 7;
    const int tile_m = (x << 6) | (k >> 3);

    const int t = threadIdx.x;
    const int lane = t & 63;
    const int wid = t >> 6;
    const int wm = wid >> 1, wn = wid & 1;

    const int row0 = tile_m * BM;
    const int col0 = tile_n * BN;

    f32x4 acc[4][4];
#pragma unroll
    for (int i = 0; i < 4; ++i)
#pragma unroll
        for (int j = 0; j < 4; ++j)
            acc[i][j] = (f32x4){0.f, 0.f, 0.f, 0.f};

    const int mrow = lane & 15;
    const int kq = (lane >> 4) * 8;

    // per-issue chunk indices: c = issue*256 + wid*64 + lane; 16B per chunk
    const int c0 = wid * 64 + lane;
    const int c1 = c0 + 256;
    const unsigned ldsA0 = (unsigned)(wid * 64) * 16;
    const unsigned ldsA1 = ldsA0 + 256 * 16;

    for (int kt = 0; kt < HDIM; kt += BK) {
        {
            const unsigned short* ga0 = encb + (size_t)(row0 + (c0 >> 2)) * HDIM + kt + (c0 & 3) * 8;
            const unsigned short* ga1 = encb + (size_t)(row0 + (c1 >> 2)) * HDIM + kt + (c1 & 3) * 8;
            const unsigned short* gb0 = W1T + (size_t)(col0 + (c0 >> 2)) * HDIM + kt + (c0 & 3) * 8;
            const unsigned short* gb1 = W1T + (size_t)(col0 + (c1 >> 2)) * HDIM + kt + (c1 & 3) * 8;
            GLDS16(ga0, (char*)As + ldsA0);
            GLDS16(ga1, (char*)As + ldsA1);
            GLDS16(gb0, (char*)Bs + ldsA0);
            GLDS16(gb1, (char*)Bs + ldsA1);
        }
        __syncthreads();   // drains vmcnt; LDS tile visible

        bf16x8 a[4], bb[4];
#pragma unroll
        for (int i = 0; i < 4; ++i)
            a[i] = *reinterpret_cast<const bf16x8*>(As + (wm * 64 + i * 16 + mrow) * BK + kq);
#pragma unroll
        for (int j = 0; j < 4; ++j)
            bb[j] = *reinterpret_cast<const bf16x8*>(Bs + (wn * 64 + j * 16 + mrow) * BK + kq);
#pragma unroll
        for (int i = 0; i < 4; ++i)
#pragma unroll
            for (int j = 0; j < 4; ++j)
                acc[i][j] = __builtin_amdgcn_mfma_f32_16x16x32_bf16(a[i], bb[j], acc[i][j], 0, 0, 0);
        __syncthreads();   // all waves done reading before next stage overwrites
    }

    // epilogue: +ph -> fast_tanh -> *Vw -> reduce over u cols -> partial slice
    const int b = row0 >> 11;          // S=2048 rows per batch; BM divides S
    const int colg = lane & 15;        // C/D: col = lane&15
    const int rowq = (lane >> 4) * 4;  // C/D: row = quad*4 + reg
    float vw[4], phv[4];
#pragma unroll
    for (int j = 0; j < 4; ++j) {
        int u = col0 + wn * 64 + j * 16 + colg;
        vw[j] = Vw[u];
        phv[j] = ph[b * UDIM + u];
    }
#pragma unroll
    for (int i = 0; i < 4; ++i) {
#pragma unroll
        for (int r = 0; r < 4; ++r) {
            float s = 0.f;
#pragma unroll
            for (int j = 0; j < 4; ++j) {
                float pe = acc[i][j][r] + phv[j];
                s += fast_tanh(pe) * vw[j];
            }
            s += __shfl_xor(s, 1);
            s += __shfl_xor(s, 2);
            s += __shfl_xor(s, 4);
            s += __shfl_xor(s, 8);
            if (colg == 0) {
                int row = row0 + wm * 64 + i * 16 + rowq + r;
                part[(size_t)(tile_n * 2 + wn) * MROWS + row] = s;
            }
        }
    }
}

// ---------------- fallback GEMM (fp32 in-register convert) ----------------
#define LDK 40
__global__ __launch_bounds__(256) void score_kernel_f32(
    const float* __restrict__ enc, const unsigned short* __restrict__ W1T,
    const float* __restrict__ ph, const float* __restrict__ Vw,
    float* __restrict__ part) {
    __shared__ unsigned short As[BM * LDK];
    __shared__ unsigned short Bs[BN * LDK];

    const int bx = blockIdx.x;
    const int tile_n = bx & 7;
    const int tile_m = bx >> 3;
    const int t = threadIdx.x;
    const int lane = t & 63;
    const int wid = t >> 6;
    const int wm = wid >> 1, wn = wid & 1;

    const int row0 = tile_m * BM;
    const int col0 = tile_n * BN;

    f32x4 acc[4][4];
#pragma unroll
    for (int i = 0; i < 4; ++i)
#pragma unroll
        for (int j = 0; j < 4; ++j)
            acc[i][j] = (f32x4){0.f, 0.f, 0.f, 0.f};

    const int mrow = lane & 15;
    const int kq = (lane >> 4) * 8;

    for (int kt = 0; kt < HDIM; kt += BK) {
        __syncthreads();
#pragma unroll
        for (int i = 0; i < 4; ++i) {
            int c = t + 256 * i;
            int r = c >> 3;
            int kc = (c & 7) * 4;
            const float4 f = *(const float4*)(enc + (size_t)(row0 + r) * HDIM + kt + kc);
            ushort4 h;
            h.x = f2bf(f.x); h.y = f2bf(f.y); h.z = f2bf(f.z); h.w = f2bf(f.w);
            *(ushort4*)(As + r * LDK + kc) = h;
        }
#pragma unroll
        for (int i = 0; i < 2; ++i) {
            int c = t + 256 * i;
            int r = c >> 2;
            int kc = (c & 3) * 8;
            const uint4 v = *(const uint4*)(W1T + (size_t)(col0 + r) * HDIM + kt + kc);
            *(uint4*)(Bs + r * LDK + kc) = v;
        }
        __syncthreads();

        bf16x8 a[4], bb[4];
#pragma unroll
        for (int i = 0; i < 4; ++i)
            a[i] = *reinterpret_cast<const bf16x8*>(As + (wm * 64 + i * 16 + mrow) * LDK + kq);
#pragma unroll
        for (int j = 0; j < 4; ++j)
            bb[j] = *reinterpret_cast<const bf16x8*>(Bs + (wn * 64 + j * 16 + mrow) * LDK + kq);
#pragma unroll
        for (int i = 0; i < 4; ++i)
#pragma unroll
            for (int j = 0; j < 4; ++j)
                acc[i][j] = __builtin_amdgcn_mfma_f32_16x16x32_bf16(a[i], bb[j], acc[i][j], 0, 0, 0);
    }

    const int b = row0 >> 11;
    const int colg = lane & 15;
    const int rowq = (lane >> 4) * 4;
    float vw[4], phv[4];
#pragma unroll
    for (int j = 0; j < 4; ++j) {
        int u = col0 + wn * 64 + j * 16 + colg;
        vw[j] = Vw[u];
        phv[j] = ph[b * UDIM + u];
    }
#pragma unroll
    for (int i = 0; i < 4; ++i) {
#pragma unroll
        for (int r = 0; r < 4; ++r) {
            float s = 0.f;
#pragma unroll
            for (int j = 0; j < 4; ++j) {
                float pe = acc[i][j][r] + phv[j];
                s += fast_tanh(pe) * vw[j];
            }
            s += __shfl_xor(s, 1);
            s += __shfl_xor(s, 2);
            s += __shfl_xor(s, 4);
            s += __shfl_xor(s, 8);
            if (colg == 0) {
                int row = row0 + wm * 64 + i * 16 + rowq + r;
                part[(size_t)(tile_n * 2 + wn) * MROWS + row] = s;
            }
        }
    }
}

// ---------------- final: sum 16 partial slices + softmax over s ----------------
__global__ void softmax_kernel(const float* __restrict__ part, float* __restrict__ out) {
    int b = blockIdx.x;
    int t = threadIdx.x;   // 256
    __shared__ float sred[4];
    float v[8];
    float lmax = -3.4e38f;
#pragma unroll
    for (int i = 0; i < 8; ++i) {
        int s = t + i * 256;
        float sum = 0.f;
#pragma unroll
        for (int p = 0; p < 16; ++p) sum += part[(size_t)p * MROWS + b * SDIM + s];
        v[i] = sum;
        lmax = fmaxf(lmax, sum);
    }
#pragma unroll
    for (int off = 1; off < 64; off <<= 1) lmax = fmaxf(lmax, __shfl_xor(lmax, off));
    if ((t & 63) == 0) sred[t >> 6] = lmax;
    __syncthreads();
    float bmax = fmaxf(fmaxf(sred[0], sred[1]), fmaxf(sred[2], sred[3]));
    __syncthreads();
    float lsum = 0.f;
#pragma unroll
    for (int i = 0; i < 8; ++i) {
        v[i] = expf(v[i] - bmax);
        lsum += v[i];
    }
#pragma unroll
    for (int off = 1; off < 64; off <<= 1) lsum += __shfl_xor(lsum, off);
    if ((t & 63) == 0) sred[t >> 6] = lsum;
    __syncthreads();
    float inv = 1.0f / (sred[0] + sred[1] + sred[2] + sred[3]);
#pragma unroll
    for (int i = 0; i < 8; ++i) out[b * SDIM + t + i * 256] = v[i] * inv;
}

extern "C" void kernel_launch(void* const* d_in, const int* in_sizes, int n_in,
                              void* d_out, int out_size, void* d_ws, size_t ws_size,
                              hipStream_t stream) {
    const float* enc = (const float*)d_in[0];
    const float* hn  = (const float*)d_in[1];
    const float* W1  = (const float*)d_in[2];
    const float* W1b = (const float*)d_in[3];
    const float* W2  = (const float*)d_in[4];
    const float* W2b = (const float*)d_in[5];
    const float* Vw  = (const float*)d_in[6];
    // d_in[7] = V_b: softmax is shift-invariant per batch -> exactly cancels.
    float* out = (float*)d_out;

    char* ws = (char*)d_ws;
    const size_t ENCB_BYTES = (size_t)MROWS * HDIM * 2;        // 128 MB
    const size_t NEED = ENCB_BYTES + (2u << 20) + (128u << 10) + (1u << 20) + (4u << 20);

    if (ws_size >= NEED) {
        unsigned short* encb = (unsigned short*)ws;                                  // 128 MB
        unsigned short* W1T  = (unsigned short*)(ws + ENCB_BYTES);                   // 2 MB
        float* ph   = (float*)(ws + ENCB_BYTES + (2u << 20));                        // 128 KB
        float* php  = (float*)(ws + ENCB_BYTES + (2u << 20) + (128u << 10));         // 1 MB
        float* part = (float*)(ws + ENCB_BYTES + (2u << 20) + (128u << 10) + (1u << 20)); // 4 MB

        cvt_kernel<<<32768, 256, 0, stream>>>(enc, encb);
        w1t_kernel<<<dim3(32, 32), dim3(32, 8), 0, stream>>>(W1, W1T);
        php_kernel<<<dim3(4, 32, 8), 256, 0, stream>>>(hn, W2, php);
        ph_combine<<<128, 256, 0, stream>>>(php, W1b, W2b, ph);
        score_kernel<<<dim3(4096), 256, 0, stream>>>(encb, W1T, ph, Vw, part);
        softmax_kernel<<<32, 256, 0, stream>>>(part, out);
    } else {
        unsigned short* W1T = (unsigned short*)ws;
        float* ph   = (float*)(ws + (2u << 20));
        float* php  = (float*)(ws + (2u << 20) + (128u << 10));
        float* part = (float*)(ws + (2u << 20) + (128u << 10) + (1u << 20));

        w1t_kernel<<<dim3(32, 32), dim3(32, 8), 0, stream>>>(W1, W1T);
        php_kernel<<<dim3(4, 32, 8), 256, 0, stream>>>(hn, W2, php);
        ph_combine<<<128, 256, 0, stream>>>(php, W1b, W2b, ph);
        score_kernel_f32<<<dim3(4096), 256, 0, stream>>>(enc, W1T, ph, Vw, part);
        softmax_kernel<<<32, 256, 0, stream>>>(part, out);
    }
}

// Round 4
// 591.952 us; speedup vs baseline: 1.0842x; 1.0076x over previous
//
#include <hip/hip_runtime.h>
#include <hip/hip_bf16.h>

// B=32, S=2048, H=1024, U=1024. M = B*S = 65536 rows.
// score[b,s] = sum_u tanh(enc[b,s,:]@W1[:,u] + W1b[u] + ph[b,u]) * Vw[u]  (+Vb cancels in softmax)
// out = softmax_s(score)

typedef __bf16 bf16x8 __attribute__((ext_vector_type(8)));
typedef float  f32x4  __attribute__((ext_vector_type(4)));

#define HDIM 1024
#define UDIM 1024
#define SDIM 2048
#define MROWS 65536
#define BM 128
#define BN 128
#define BK 32

__device__ inline unsigned short f2bf(float x) {
    return __builtin_bit_cast(unsigned short, (__bf16)x);
}

// fast tanh: tanh(x) = sign(x) * (1-e^{-2|x|})/(1+e^{-2|x|}). z in (0,1].
__device__ inline float fast_tanh(float x) {
    float z = __expf(-2.0f * __builtin_fabsf(x));
    float t = __fdividef(1.0f - z, 1.0f + z);
    return __builtin_copysignf(t, x);
}

// async 16B global->LDS (m97: width=16 emits global_load_lds_dwordx4)
#define GLDS16(gp, lp)                                                              \
    __builtin_amdgcn_global_load_lds(                                               \
        (const __attribute__((address_space(1))) unsigned int*)(gp),                \
        (__attribute__((address_space(3))) unsigned int*)(lp), 16, 0, 0)

// ---------------- prep: enc fp32 -> bf16 (pure BW pass) ----------------
__global__ __launch_bounds__(256) void cvt_kernel(const float* __restrict__ in,
                                                  unsigned short* __restrict__ out) {
    size_t i = ((size_t)blockIdx.x * 256 + threadIdx.x) * 8;
    const float4 f0 = *(const float4*)(in + i);
    const float4 f1 = *(const float4*)(in + i + 4);
    ushort4 h0, h1;
    h0.x = f2bf(f0.x); h0.y = f2bf(f0.y); h0.z = f2bf(f0.z); h0.w = f2bf(f0.w);
    h1.x = f2bf(f1.x); h1.y = f2bf(f1.y); h1.z = f2bf(f1.z); h1.w = f2bf(f1.w);
    *(ushort4*)(out + i) = h0;
    *(ushort4*)(out + i + 4) = h1;
}

// ---------------- prep: W1 [H,U] fp32 -> W1T [U,H] bf16 ----------------
__global__ void w1t_kernel(const float* __restrict__ W1, unsigned short* __restrict__ W1T) {
    __shared__ float tile[32][33];
    int bx = blockIdx.x;   // u tile
    int by = blockIdx.y;   // h tile
    int tx = threadIdx.x, ty = threadIdx.y;   // (32,8)
#pragma unroll
    for (int r = 0; r < 4; ++r) {
        int h = by * 32 + ty + r * 8;
        int u = bx * 32 + tx;
        tile[ty + r * 8][tx] = W1[h * UDIM + u];
    }
    __syncthreads();
#pragma unroll
    for (int r = 0; r < 4; ++r) {
        int u = bx * 32 + ty + r * 8;
        int h = by * 32 + tx;
        W1T[u * HDIM + h] = f2bf(tile[tx][ty + r * 8]);
    }
}

// ---------------- prep: ph partials (split-K over h) ----------------
__global__ void php_kernel(const float* __restrict__ hn, const float* __restrict__ W2,
                           float* __restrict__ php) {
    int u = (blockIdx.x & 3) * 256 + threadIdx.x;
    int b = blockIdx.y;
    int hc = blockIdx.z;           // 8 chunks of 128
    int h0 = hc * 128;
    float acc = 0.f;
#pragma unroll 8
    for (int h = h0; h < h0 + 128; ++h)
        acc = fmaf(hn[b * HDIM + h], W2[h * UDIM + u], acc);
    php[(hc * 32 + b) * UDIM + u] = acc;
}

__global__ void ph_combine(const float* __restrict__ php, const float* __restrict__ W1b,
                           const float* __restrict__ W2b, float* __restrict__ ph) {
    int idx = blockIdx.x * 256 + threadIdx.x;   // 32768
    int u = idx & (UDIM - 1);
    int b = idx >> 10;
    float acc = W1b[u] + W2b[u];
#pragma unroll
    for (int p = 0; p < 8; ++p) acc += php[(p * 32 + b) * UDIM + u];
    ph[idx] = acc;
}

// ---------------- main fused GEMM (async staging + XOR-swizzled LDS) ----------------
// LDS layout: physical 16B chunk p holds logical (row = p>>2, kchunk = (p&3) ^ ((row>>1)&3)).
// Staging: lane writes chunk p = issue*256+wid*64+lane (contiguous, global_load_lds-legal);
//   the XOR only permutes 16B pieces inside each row's 64B global window -> coalescing intact.
// Read: fragment (row, kc) lives at (row*4 + (kc ^ ((row>>1)&3)))*16 -> lanes 0..15 spread
//   over 8 bank-quads at 2 lanes each = conflict-free (m136: 2-way is free; old layout was 8-way).
__global__ __launch_bounds__(256) void score_kernel(
    const unsigned short* __restrict__ encb, const unsigned short* __restrict__ W1T,
    const float* __restrict__ ph, const float* __restrict__ Vw,
    float* __restrict__ part) {
    __shared__ unsigned short As[BM * BK];   // 8192 B
    __shared__ unsigned short Bs[BN * BK];   // 8192 B

    const int bx = blockIdx.x;
    // XCD swizzle: bx&7 -> XCD; each XCD owns a 64-tile m-slab, n-fastest inside.
    const int x = bx & 7;
    const int k = bx >> 3;
    const int tile_n = k & 7;
    const int tile_m = (x << 6) | (k >> 3);

    const int t = threadIdx.x;
    const int lane = t & 63;
    const int wid = t >> 6;
    const int wm = wid >> 1, wn = wid & 1;

    const int row0 = tile_m * BM;
    const int col0 = tile_n * BN;

    f32x4 acc[4][4];
#pragma unroll
    for (int i = 0; i < 4; ++i)
#pragma unroll
        for (int j = 0; j < 4; ++j)
            acc[i][j] = (f32x4){0.f, 0.f, 0.f, 0.f};

    const int mrow = lane & 15;
    // swizzled k-chunk for fragment reads: (lane>>4) ^ ((row>>1)&3); row's bits 1-2 == mrow's.
    const int kcs = ((lane >> 4) ^ ((mrow >> 1) & 3)) * 8;   // element offset

    // staging chunks: c = issue*256 + wid*64 + lane; row = c>>2; logical kchunk = (c&3)^((c>>3)&3)
    const int c0 = wid * 64 + lane;
    const int c1 = c0 + 256;
    const int r0c = c0 >> 2, r1c = c1 >> 2;
    const int kl0 = ((c0 & 3) ^ ((c0 >> 3) & 3)) * 8;
    const int kl1 = ((c1 & 3) ^ ((c1 >> 3) & 3)) * 8;
    const unsigned ldsA0 = (unsigned)(wid * 64) * 16;
    const unsigned ldsA1 = ldsA0 + 256 * 16;

    for (int kt = 0; kt < HDIM; kt += BK) {
        {
            const unsigned short* ga0 = encb + (size_t)(row0 + r0c) * HDIM + kt + kl0;
            const unsigned short* ga1 = encb + (size_t)(row0 + r1c) * HDIM + kt + kl1;
            const unsigned short* gb0 = W1T + (size_t)(col0 + r0c) * HDIM + kt + kl0;
            const unsigned short* gb1 = W1T + (size_t)(col0 + r1c) * HDIM + kt + kl1;
            GLDS16(ga0, (char*)As + ldsA0);
            GLDS16(ga1, (char*)As + ldsA1);
            GLDS16(gb0, (char*)Bs + ldsA0);
            GLDS16(gb1, (char*)Bs + ldsA1);
        }
        __syncthreads();   // drains vmcnt; LDS tile visible

        bf16x8 a[4], bb[4];
#pragma unroll
        for (int i = 0; i < 4; ++i)
            a[i] = *reinterpret_cast<const bf16x8*>(As + (wm * 64 + i * 16 + mrow) * BK + kcs);
#pragma unroll
        for (int j = 0; j < 4; ++j)
            bb[j] = *reinterpret_cast<const bf16x8*>(Bs + (wn * 64 + j * 16 + mrow) * BK + kcs);
#pragma unroll
        for (int i = 0; i < 4; ++i)
#pragma unroll
            for (int j = 0; j < 4; ++j)
                acc[i][j] = __builtin_amdgcn_mfma_f32_16x16x32_bf16(a[i], bb[j], acc[i][j], 0, 0, 0);
        __syncthreads();   // all waves done reading before next stage overwrites
    }

    // epilogue: +ph -> fast_tanh -> *Vw -> reduce over u cols -> partial slice
    const int b = row0 >> 11;          // S=2048 rows per batch; BM divides S
    const int colg = lane & 15;        // C/D: col = lane&15
    const int rowq = (lane >> 4) * 4;  // C/D: row = quad*4 + reg
    float vw[4], phv[4];
#pragma unroll
    for (int j = 0; j < 4; ++j) {
        int u = col0 + wn * 64 + j * 16 + colg;
        vw[j] = Vw[u];
        phv[j] = ph[b * UDIM + u];
    }
#pragma unroll
    for (int i = 0; i < 4; ++i) {
#pragma unroll
        for (int r = 0; r < 4; ++r) {
            float s = 0.f;
#pragma unroll
            for (int j = 0; j < 4; ++j) {
                float pe = acc[i][j][r] + phv[j];
                s += fast_tanh(pe) * vw[j];
            }
            s += __shfl_xor(s, 1);
            s += __shfl_xor(s, 2);
            s += __shfl_xor(s, 4);
            s += __shfl_xor(s, 8);
            if (colg == 0) {
                int row = row0 + wm * 64 + i * 16 + rowq + r;
                part[(size_t)(tile_n * 2 + wn) * MROWS + row] = s;
            }
        }
    }
}

// ---------------- fallback GEMM (fp32 in-register convert) ----------------
#define LDK 40
__global__ __launch_bounds__(256) void score_kernel_f32(
    const float* __restrict__ enc, const unsigned short* __restrict__ W1T,
    const float* __restrict__ ph, const float* __restrict__ Vw,
    float* __restrict__ part) {
    __shared__ unsigned short As[BM * LDK];
    __shared__ unsigned short Bs[BN * LDK];

    const int bx = blockIdx.x;
    const int tile_n = bx & 7;
    const int tile_m = bx >> 3;
    const int t = threadIdx.x;
    const int lane = t & 63;
    const int wid = t >> 6;
    const int wm = wid >> 1, wn = wid & 1;

    const int row0 = tile_m * BM;
    const int col0 = tile_n * BN;

    f32x4 acc[4][4];
#pragma unroll
    for (int i = 0; i < 4; ++i)
#pragma unroll
        for (int j = 0; j < 4; ++j)
            acc[i][j] = (f32x4){0.f, 0.f, 0.f, 0.f};

    const int mrow = lane & 15;
    const int kq = (lane >> 4) * 8;

    for (int kt = 0; kt < HDIM; kt += BK) {
        __syncthreads();
#pragma unroll
        for (int i = 0; i < 4; ++i) {
            int c = t + 256 * i;
            int r = c >> 3;
            int kc = (c & 7) * 4;
            const float4 f = *(const float4*)(enc + (size_t)(row0 + r) * HDIM + kt + kc);
            ushort4 h;
            h.x = f2bf(f.x); h.y = f2bf(f.y); h.z = f2bf(f.z); h.w = f2bf(f.w);
            *(ushort4*)(As + r * LDK + kc) = h;
        }
#pragma unroll
        for (int i = 0; i < 2; ++i) {
            int c = t + 256 * i;
            int r = c >> 2;
            int kc = (c & 3) * 8;
            const uint4 v = *(const uint4*)(W1T + (size_t)(col0 + r) * HDIM + kt + kc);
            *(uint4*)(Bs + r * LDK + kc) = v;
        }
        __syncthreads();

        bf16x8 a[4], bb[4];
#pragma unroll
        for (int i = 0; i < 4; ++i)
            a[i] = *reinterpret_cast<const bf16x8*>(As + (wm * 64 + i * 16 + mrow) * LDK + kq);
#pragma unroll
        for (int j = 0; j < 4; ++j)
            bb[j] = *reinterpret_cast<const bf16x8*>(Bs + (wn * 64 + j * 16 + mrow) * LDK + kq);
#pragma unroll
        for (int i = 0; i < 4; ++i)
#pragma unroll
            for (int j = 0; j < 4; ++j)
                acc[i][j] = __builtin_amdgcn_mfma_f32_16x16x32_bf16(a[i], bb[j], acc[i][j], 0, 0, 0);
    }

    const int b = row0 >> 11;
    const int colg = lane & 15;
    const int rowq = (lane >> 4) * 4;
    float vw[4], phv[4];
#pragma unroll
    for (int j = 0; j < 4; ++j) {
        int u = col0 + wn * 64 + j * 16 + colg;
        vw[j] = Vw[u];
        phv[j] = ph[b * UDIM + u];
    }
#pragma unroll
    for (int i = 0; i < 4; ++i) {
#pragma unroll
        for (int r = 0; r < 4; ++r) {
            float s = 0.f;
#pragma unroll
            for (int j = 0; j < 4; ++j) {
                float pe = acc[i][j][r] + phv[j];
                s += fast_tanh(pe) * vw[j];
            }
            s += __shfl_xor(s, 1);
            s += __shfl_xor(s, 2);
            s += __shfl_xor(s, 4);
            s += __shfl_xor(s, 8);
            if (colg == 0) {
                int row = row0 + wm * 64 + i * 16 + rowq + r;
                part[(size_t)(tile_n * 2 + wn) * MROWS + row] = s;
            }
        }
    }
}

// ---------------- final: sum 16 partial slices + softmax over s ----------------
__global__ void softmax_kernel(const float* __restrict__ part, float* __restrict__ out) {
    int b = blockIdx.x;
    int t = threadIdx.x;   // 256
    __shared__ float sred[4];
    float v[8];
    float lmax = -3.4e38f;
#pragma unroll
    for (int i = 0; i < 8; ++i) {
        int s = t + i * 256;
        float sum = 0.f;
#pragma unroll
        for (int p = 0; p < 16; ++p) sum += part[(size_t)p * MROWS + b * SDIM + s];
        v[i] = sum;
        lmax = fmaxf(lmax, sum);
    }
#pragma unroll
    for (int off = 1; off < 64; off <<= 1) lmax = fmaxf(lmax, __shfl_xor(lmax, off));
    if ((t & 63) == 0) sred[t >> 6] = lmax;
    __syncthreads();
    float bmax = fmaxf(fmaxf(sred[0], sred[1]), fmaxf(sred[2], sred[3]));
    __syncthreads();
    float lsum = 0.f;
#pragma unroll
    for (int i = 0; i < 8; ++i) {
        v[i] = expf(v[i] - bmax);
        lsum += v[i];
    }
#pragma unroll
    for (int off = 1; off < 64; off <<= 1) lsum += __shfl_xor(lsum, off);
    if ((t & 63) == 0) sred[t >> 6] = lsum;
    __syncthreads();
    float inv = 1.0f / (sred[0] + sred[1] + sred[2] + sred[3]);
#pragma unroll
    for (int i = 0; i < 8; ++i) out[b * SDIM + t + i * 256] = v[i] * inv;
}

extern "C" void kernel_launch(void* const* d_in, const int* in_sizes, int n_in,
                              void* d_out, int out_size, void* d_ws, size_t ws_size,
                              hipStream_t stream) {
    const float* enc = (const float*)d_in[0];
    const float* hn  = (const float*)d_in[1];
    const float* W1  = (const float*)d_in[2];
    const float* W1b = (const float*)d_in[3];
    const float* W2  = (const float*)d_in[4];
    const float* W2b = (const float*)d_in[5];
    const float* Vw  = (const float*)d_in[6];
    // d_in[7] = V_b: softmax is shift-invariant per batch -> exactly cancels.
    float* out = (float*)d_out;

    char* ws = (char*)d_ws;
    const size_t ENCB_BYTES = (size_t)MROWS * HDIM * 2;        // 128 MB
    const size_t NEED = ENCB_BYTES + (2u << 20) + (128u << 10) + (1u << 20) + (4u << 20);

    if (ws_size >= NEED) {
        unsigned short* encb = (unsigned short*)ws;                                  // 128 MB
        unsigned short* W1T  = (unsigned short*)(ws + ENCB_BYTES);                   // 2 MB
        float* ph   = (float*)(ws + ENCB_BYTES + (2u << 20));                        // 128 KB
        float* php  = (float*)(ws + ENCB_BYTES + (2u << 20) + (128u << 10));         // 1 MB
        float* part = (float*)(ws + ENCB_BYTES + (2u << 20) + (128u << 10) + (1u << 20)); // 4 MB

        cvt_kernel<<<32768, 256, 0, stream>>>(enc, encb);
        w1t_kernel<<<dim3(32, 32), dim3(32, 8), 0, stream>>>(W1, W1T);
        php_kernel<<<dim3(4, 32, 8), 256, 0, stream>>>(hn, W2, php);
        ph_combine<<<128, 256, 0, stream>>>(php, W1b, W2b, ph);
        score_kernel<<<dim3(4096), 256, 0, stream>>>(encb, W1T, ph, Vw, part);
        softmax_kernel<<<32, 256, 0, stream>>>(part, out);
    } else {
        unsigned short* W1T = (unsigned short*)ws;
        float* ph   = (float*)(ws + (2u << 20));
        float* php  = (float*)(ws + (2u << 20) + (128u << 10));
        float* part = (float*)(ws + (2u << 20) + (128u << 10) + (1u << 20));

        w1t_kernel<<<dim3(32, 32), dim3(32, 8), 0, stream>>>(W1, W1T);
        php_kernel<<<dim3(4, 32, 8), 256, 0, stream>>>(hn, W2, php);
        ph_combine<<<128, 256, 0, stream>>>(php, W1b, W2b, ph);
        score_kernel_f32<<<dim3(4096), 256, 0, stream>>>(enc, W1T, ph, Vw, part);
        softmax_kernel<<<32, 256, 0, stream>>>(part, out);
    }
}